// Round 7
// baseline (280.558 us; speedup 1.0000x reference)
//
#include <hip/hip_runtime.h>

typedef __attribute__((ext_vector_type(8))) short short8;
typedef __attribute__((ext_vector_type(4))) float float4v;

#define P1B   256    // edge-chunk blocks for the count pass (fused_pre)
#define B3    64     // bucketize blocks: CH/G ~ 16 edges -> 64B write runs
#define GS    64     // nodes per bucketize group
#define GSH   6      // log2(GS)
#define AGS   32     // nodes per aggregate block (half-group filter)
#define ELCAP 768    // LDS edge slots per half-group; mean 512, +11 sigma
#define GCAP  2048   // max groups+1 supported (N <= 131072)

__device__ __forceinline__ unsigned short f2bf(float f) {
    union { float f; unsigned u; } v; v.f = f;
    unsigned r = v.u + 0x7fffu + ((v.u >> 16) & 1u);   // round-to-nearest-even
    return (unsigned short)(r >> 16);
}
__device__ __forceinline__ float bf2f(unsigned short u) {
    union { unsigned u; float f; } v; v.u = ((unsigned)u) << 16; return v.f;
}

// ---------------- K1: fused [group-count | LN+ReLU | W-prep] ------------
__global__ __launch_bounds__(256) void fused_pre_kernel(
    const float* __restrict__ x, const float* __restrict__ gamma,
    const float* __restrict__ beta, unsigned* __restrict__ hbuf,
    const int* __restrict__ idx, int* __restrict__ gdeg,
    const float* __restrict__ Wl, const float* __restrict__ Wr,
    unsigned short* __restrict__ wsb, int N, int E, int LNB, int G) {
    const int b = blockIdx.x, t = threadIdx.x;
    if (b < P1B) {
        __shared__ int hist[GCAP];
        for (int i = t; i < G; i += 256) hist[i] = 0;
        __syncthreads();
        const int CH = (E + P1B - 1) / P1B;
        const int e0 = b * CH, e1 = min(E, e0 + CH);
        for (int e = e0 + t; e < e1; e += 256)
            atomicAdd(&hist[idx[E + e] >> GSH], 1);
        __syncthreads();
        for (int i = t; i < G; i += 256)
            if (hist[i]) atomicAdd(&gdeg[i], hist[i]);
    } else if (b < P1B + LNB) {
        const int row = (b - P1B) * 4 + (t >> 6);
        if (row >= N) return;
        const int lane = t & 63;
        const size_t base = (size_t)row * 128 + lane * 2;
        float2 v = *(const float2*)&x[base];
        float s = v.x + v.y;
        #pragma unroll
        for (int o = 32; o; o >>= 1) s += __shfl_xor(s, o, 64);
        const float mu = s * 0.0078125f;
        const float d0 = v.x - mu, d1 = v.y - mu;
        float ss = d0 * d0 + d1 * d1;
        #pragma unroll
        for (int o = 32; o; o >>= 1) ss += __shfl_xor(ss, o, 64);
        const float rs = rsqrtf(ss * 0.0078125f + 1e-5f);
        float2 g = *(const float2*)&gamma[lane * 2];
        float2 bb = *(const float2*)&beta[lane * 2];
        float h0 = fmaxf(fmaf(d0 * rs, g.x, bb.x), 0.f);
        float h1 = fmaxf(fmaf(d1 * rs, g.y, bb.y), 0.f);
        hbuf[(size_t)row * 64 + lane] = (unsigned)f2bf(h0) | ((unsigned)f2bf(h1) << 16);
    } else {
        const int s = (b - P1B - LNB) * 256 + t;     // 0..4095
        const int tc = s >> 9, c = (s >> 6) & 7, l = s & 63;
        const int n  = tc * 16 + (l & 15);
        const int k0 = c * 32 + ((l >> 4) & 3) * 8;
        const float* w = (k0 < 128) ? (Wl + (size_t)n * 128 + k0)
                                    : (Wr + (size_t)n * 128 + (k0 - 128));
        unsigned short tmp[8];
        #pragma unroll
        for (int j = 0; j < 8; j++) tmp[j] = f2bf(w[j]);
        *(short8*)&wsb[(size_t)s * 8] = *(short8*)tmp;
    }
}

// ---------------- K2: scan group totals -> gstart[G+1], gcur ------------
__global__ __launch_bounds__(1024) void gscan_kernel(
    const int* __restrict__ gdeg, int* __restrict__ gstart,
    int* __restrict__ gcur, int G) {
    __shared__ int sd[1024];
    const int t = threadIdx.x;
    const int i0 = 2 * t, i1 = 2 * t + 1;
    const int v0 = (i0 < G) ? gdeg[i0] : 0;
    const int v1 = (i1 < G) ? gdeg[i1] : 0;
    const int pr = v0 + v1;
    sd[t] = pr;
    __syncthreads();
    for (int off = 1; off < 1024; off <<= 1) {
        int u = (t >= off) ? sd[t - off] : 0;
        __syncthreads();
        sd[t] += u;
        __syncthreads();
    }
    const int ex = sd[t] - pr;
    if (i0 <= G) { gstart[i0] = ex;      if (i0 < G) gcur[i0] = ex; }
    if (i1 <= G) { gstart[i1] = ex + v0; if (i1 < G) gcur[i1] = ex + v0; }
}

// ---------------- K3: coarse bucketize edges into groups ----------------
// Packs (src<<6 | dst&63). B3=64 blocks -> per-(block,group) runs avg
// CH/G ~ 16 edges = 64B: full-line scatter writes (r4's P1B=256 gave
// 16B runs -> partial-line churn). gdeg/gscan are chunk-independent,
// so only this kernel's grid changes.
__global__ __launch_bounds__(1024) void bucketize_kernel(
    const int* __restrict__ idx, int* __restrict__ gcur,
    int* __restrict__ gbuf, int E, int G) {
    __shared__ int hist[GCAP], base[GCAP];
    const int t = threadIdx.x, b = blockIdx.x;
    for (int i = t; i < G; i += 1024) hist[i] = 0;
    __syncthreads();
    const int CH = (E + B3 - 1) / B3;
    const int e0 = b * CH, e1 = min(E, e0 + CH);
    for (int e = e0 + t; e < e1; e += 1024)
        atomicAdd(&hist[idx[E + e] >> GSH], 1);
    __syncthreads();
    for (int i = t; i < G; i += 1024) {
        const int c = hist[i];
        base[i] = c ? atomicAdd(&gcur[i], c) : 0;
        hist[i] = 0;
    }
    __syncthreads();
    for (int e = e0 + t; e < e1; e += 1024) {
        const int dst = idx[E + e];
        const int src = idx[e];
        const int g = dst >> GSH;
        const int pos = base[g] + atomicAdd(&hist[g], 1);
        gbuf[pos] = (src << GSH) | (dst & (GS - 1));   // src < 2^(32-GSH)
    }
}

// ---------------- K4: half-group counting-sort + register gather --------
// Round-4 proven body; the ONLY gather change is widening the uniform
// elds reads: 2x ds_read_b128 per 8-edge batch instead of 8x ds_read_b32
// (lgkm chain ~48 -> ~24 cy/batch). Lane ownership, row loads, unpack
// all unchanged (r5's lane-split regressed). float2 acc lets adjacent
// adds fuse to v_pk_add_f32.
__global__ __launch_bounds__(256) void aggregate_kernel(
    const unsigned* __restrict__ hbuf, const int* __restrict__ gbuf,
    const int* __restrict__ gstart, unsigned* __restrict__ mbuf, int N) {
    __shared__ __align__(16) int elds[ELCAP];      // 3 KB sorted src
    __shared__ int hist[AGS], segstart[AGS], cur[AGS];
    const int t = threadIdx.x, w = t >> 6, l = t & 63;
    const int b = blockIdx.x;
    const int g = b >> 1, half = b & 1;
    const int n0 = b << 5;                         // = g*64 + half*32
    const int e0 = gstart[g], cnt = gstart[g + 1] - e0;

    if (t < AGS) hist[t] = 0;
    __syncthreads();
    for (int i = t; i < cnt; i += 256) {
        const int r = gbuf[e0 + i] & (GS - 1);
        if ((r >> 5) == half) atomicAdd(&hist[r & (AGS - 1)], 1);
    }
    __syncthreads();
    if (t < AGS) cur[t] = hist[t];
    __syncthreads();
    for (int off = 1; off < AGS; off <<= 1) {
        int u = (t < AGS && t >= off) ? cur[t - off] : 0;
        __syncthreads();
        if (t < AGS) cur[t] += u;
        __syncthreads();
    }
    if (t < AGS) { segstart[t] = cur[t] - hist[t]; cur[t] = segstart[t]; }
    __syncthreads();
    for (int i = t; i < cnt; i += 256) {
        const int pk = gbuf[e0 + i];
        const int r = pk & (GS - 1);
        if ((r >> 5) == half) {
            const int pos = atomicAdd(&cur[r & (AGS - 1)], 1);
            if (pos < ELCAP) elds[pos] = pk >> GSH;
        }
    }
    __syncthreads();

    // wave w gathers nodes w*8 .. w*8+7 (register accumulate, 8-deep ILP)
    for (int i = 0; i < 8; i++) {
        const int ln = w * 8 + i;
        const int node = n0 + ln;
        const int sp = segstart[ln];
        int dend = sp + hist[ln];
        if (dend > ELCAP) dend = ELCAP;
        float2 a = make_float2(0.f, 0.f);
        int j = sp;
        while (j < dend && (j & 3)) {              // align j to 16B for b128
            const unsigned p = hbuf[(size_t)elds[j] * 64 + l];
            union { unsigned u; float f; } lo, hi;
            lo.u = p << 16; hi.u = p & 0xffff0000u;
            a.x += lo.f; a.y += hi.f;
            j++;
        }
        for (; j + 8 <= dend; j += 8) {
            const int4 q0 = *(const int4*)&elds[j];     // 1x ds_read_b128
            const int4 q1 = *(const int4*)&elds[j + 4]; // 1x ds_read_b128
            unsigned p[8];
            p[0] = hbuf[(size_t)q0.x * 64 + l];
            p[1] = hbuf[(size_t)q0.y * 64 + l];
            p[2] = hbuf[(size_t)q0.z * 64 + l];
            p[3] = hbuf[(size_t)q0.w * 64 + l];
            p[4] = hbuf[(size_t)q1.x * 64 + l];
            p[5] = hbuf[(size_t)q1.y * 64 + l];
            p[6] = hbuf[(size_t)q1.z * 64 + l];
            p[7] = hbuf[(size_t)q1.w * 64 + l];
            #pragma unroll
            for (int k = 0; k < 8; k++) {
                union { unsigned u; float f; } lo, hi;
                lo.u = p[k] << 16; hi.u = p[k] & 0xffff0000u;
                a.x += lo.f; a.y += hi.f;
            }
        }
        for (; j < dend; j++) {
            const unsigned p = hbuf[(size_t)elds[j] * 64 + l];
            union { unsigned u; float f; } lo, hi;
            lo.u = p << 16; hi.u = p & 0xffff0000u;
            a.x += lo.f; a.y += hi.f;
        }
        const int dv = hist[ln];
        const float inv = (dv > 0) ? 1.f / (float)dv : 0.f;  // same quantization as before
        if (node < N)
            mbuf[(size_t)node * 64 + l] =
                (unsigned)f2bf(a.x * inv) | ((unsigned)f2bf(a.y * inv) << 16);
    }
}

// ---------------- K5: dense MFMA  out = [mean||h] @ Wcat^T + bl + x -----
__global__ __launch_bounds__(256) void mm_kernel(
    float* __restrict__ out, const unsigned* __restrict__ hbuf,
    const unsigned* __restrict__ mbuf, const float* __restrict__ x,
    const unsigned short* __restrict__ wsb, const float* __restrict__ bl, int N) {
    const int t = threadIdx.x, w = t >> 6, l = t & 63;
    const int rowbase = blockIdx.x * 64 + w * 16;
    if (rowbase >= N) return;
    const int r = l & 15, q = l >> 4;
    const int arow = min(rowbase + r, N - 1);
    const unsigned short* mp = (const unsigned short*)mbuf + (size_t)arow * 128 + q * 8;
    const unsigned short* hp = (const unsigned short*)hbuf + (size_t)arow * 128 + q * 8;
    short8 af[8];                          // A-frag: row=lane&15, k=(lane>>4)*8+j
    #pragma unroll
    for (int c = 0; c < 4; c++) af[c]     = *(const short8*)(mp + c * 32);
    #pragma unroll
    for (int c = 0; c < 4; c++) af[4 + c] = *(const short8*)(hp + c * 32);
    #pragma unroll
    for (int cc = 0; cc < 8; cc++) {       // 8 col-tiles of 16
        float4v acc = {0.f, 0.f, 0.f, 0.f};
        const short8* bw = (const short8*)wsb + (size_t)cc * 512;
        #pragma unroll
        for (int c = 0; c < 8; c++)
            acc = __builtin_amdgcn_mfma_f32_16x16x32_bf16(af[c], bw[c * 64 + l], acc, 0, 0, 0);
        const int col = cc * 16 + r;
        const float blv = bl[col];
        #pragma unroll
        for (int rr = 0; rr < 4; rr++) {   // C/D: col=lane&15, row=(lane>>4)*4+rr
            const int row = rowbase + q * 4 + rr;
            if (row < N)
                out[(size_t)row * 128 + col] = acc[rr] + blv + x[(size_t)row * 128 + col];
        }
    }
}

extern "C" void kernel_launch(void* const* d_in, const int* in_sizes, int n_in,
                              void* d_out, int out_size, void* d_ws, size_t ws_size,
                              hipStream_t stream) {
    const float* x     = (const float*)d_in[0];
    const int*   ei    = (const int*)d_in[1];
    const float* gamma = (const float*)d_in[2];
    const float* beta  = (const float*)d_in[3];
    const float* Wl    = (const float*)d_in[4];
    const float* bl    = (const float*)d_in[5];
    const float* Wr    = (const float*)d_in[6];
    float* out = (float*)d_out;

    const int C = 128;
    const int N = in_sizes[0] / C;          // 100000
    const int E = in_sizes[1] / 2;          // 1600000
    const int G = (N + GS - 1) >> GSH;      // 1563 groups

    char* ws = (char*)d_ws;
    size_t off = 0;
    unsigned* hbuf = (unsigned*)(ws + off); off += (size_t)N * 256;   // 25.6 MB bf16 h
    unsigned* mbuf = (unsigned*)(ws + off); off += (size_t)N * 256;   // 25.6 MB bf16 mean
    int* gbuf      = (int*)(ws + off);      off += (size_t)E * 4;     // 6.4 MB packed edges
    int* gdeg      = (int*)(ws + off);      off += GCAP * 4;
    int* gstart    = (int*)(ws + off);      off += GCAP * 4;
    int* gcur      = (int*)(ws + off);      off += GCAP * 4;
    unsigned short* wsb = (unsigned short*)(ws + off);                // 64 KB packed W

    const int LNB = (N + 3) / 4;            // 25000 LN blocks (4 rows each)

    hipMemsetAsync(gdeg, 0, GCAP * 4, stream);
    fused_pre_kernel<<<P1B + LNB + 16, 256, 0, stream>>>(
        x, gamma, beta, hbuf, ei, gdeg, Wl, Wr, wsb, N, E, LNB, G);
    gscan_kernel<<<1, 1024, 0, stream>>>(gdeg, gstart, gcur, G);
    bucketize_kernel<<<B3, 1024, 0, stream>>>(ei, gcur, gbuf, E, G);
    aggregate_kernel<<<2 * G, 256, 0, stream>>>(hbuf, gbuf, gstart, mbuf, N);
    mm_kernel<<<(N + 63) / 64, 256, 0, stream>>>(out, hbuf, mbuf, x, wsb, bl, N);
}

// Round 8
// 255.830 us; speedup vs baseline: 1.0967x; 1.0967x over previous
//
#include <hip/hip_runtime.h>

typedef __attribute__((ext_vector_type(8))) short short8;
typedef __attribute__((ext_vector_type(4))) float float4v;

#define P1B   256    // edge-chunk blocks (count + bucketize)
#define GS    64     // nodes per bucketize group (16B runs in gbuf scatter)
#define GSH   6      // log2(GS)
#define AGS   32     // nodes per aggregate block (half-group filter)
#define ELCAP 768    // LDS edge slots per half-group; mean 512, +11 sigma
#define GCAP  2048   // max groups+1 supported (N <= 131072)

__device__ __forceinline__ unsigned short f2bf(float f) {
    union { float f; unsigned u; } v; v.f = f;
    unsigned r = v.u + 0x7fffu + ((v.u >> 16) & 1u);   // round-to-nearest-even
    return (unsigned short)(r >> 16);
}
__device__ __forceinline__ float bf2f(unsigned short u) {
    union { unsigned u; float f; } v; v.u = ((unsigned)u) << 16; return v.f;
}

// ---------------- K1: fused [group-count | LN+ReLU | W-prep] ------------
__global__ __launch_bounds__(256) void fused_pre_kernel(
    const float* __restrict__ x, const float* __restrict__ gamma,
    const float* __restrict__ beta, unsigned* __restrict__ hbuf,
    const int* __restrict__ idx, int* __restrict__ gdeg,
    const float* __restrict__ Wl, const float* __restrict__ Wr,
    unsigned short* __restrict__ wsb, int N, int E, int LNB, int G) {
    const int b = blockIdx.x, t = threadIdx.x;
    if (b < P1B) {
        __shared__ int hist[GCAP];
        for (int i = t; i < G; i += 256) hist[i] = 0;
        __syncthreads();
        const int CH = (E + P1B - 1) / P1B;
        const int e0 = b * CH, e1 = min(E, e0 + CH);
        for (int e = e0 + t; e < e1; e += 256)
            atomicAdd(&hist[idx[E + e] >> GSH], 1);
        __syncthreads();
        for (int i = t; i < G; i += 256)
            if (hist[i]) atomicAdd(&gdeg[i], hist[i]);
    } else if (b < P1B + LNB) {
        const int row = (b - P1B) * 4 + (t >> 6);
        if (row >= N) return;
        const int lane = t & 63;
        const size_t base = (size_t)row * 128 + lane * 2;
        float2 v = *(const float2*)&x[base];
        float s = v.x + v.y;
        #pragma unroll
        for (int o = 32; o; o >>= 1) s += __shfl_xor(s, o, 64);
        const float mu = s * 0.0078125f;
        const float d0 = v.x - mu, d1 = v.y - mu;
        float ss = d0 * d0 + d1 * d1;
        #pragma unroll
        for (int o = 32; o; o >>= 1) ss += __shfl_xor(ss, o, 64);
        const float rs = rsqrtf(ss * 0.0078125f + 1e-5f);
        float2 g = *(const float2*)&gamma[lane * 2];
        float2 bb = *(const float2*)&beta[lane * 2];
        float h0 = fmaxf(fmaf(d0 * rs, g.x, bb.x), 0.f);
        float h1 = fmaxf(fmaf(d1 * rs, g.y, bb.y), 0.f);
        hbuf[(size_t)row * 64 + lane] = (unsigned)f2bf(h0) | ((unsigned)f2bf(h1) << 16);
    } else {
        const int s = (b - P1B - LNB) * 256 + t;     // 0..4095
        const int tc = s >> 9, c = (s >> 6) & 7, l = s & 63;
        const int n  = tc * 16 + (l & 15);
        const int k0 = c * 32 + ((l >> 4) & 3) * 8;
        const float* w = (k0 < 128) ? (Wl + (size_t)n * 128 + k0)
                                    : (Wr + (size_t)n * 128 + (k0 - 128));
        unsigned short tmp[8];
        #pragma unroll
        for (int j = 0; j < 8; j++) tmp[j] = f2bf(w[j]);
        *(short8*)&wsb[(size_t)s * 8] = *(short8*)tmp;
    }
}

// ---------------- K2: scan group totals -> gstart[G+1], gcur ------------
__global__ __launch_bounds__(1024) void gscan_kernel(
    const int* __restrict__ gdeg, int* __restrict__ gstart,
    int* __restrict__ gcur, int G) {
    __shared__ int sd[1024];
    const int t = threadIdx.x;
    const int i0 = 2 * t, i1 = 2 * t + 1;
    const int v0 = (i0 < G) ? gdeg[i0] : 0;
    const int v1 = (i1 < G) ? gdeg[i1] : 0;
    const int pr = v0 + v1;
    sd[t] = pr;
    __syncthreads();
    for (int off = 1; off < 1024; off <<= 1) {
        int u = (t >= off) ? sd[t - off] : 0;
        __syncthreads();
        sd[t] += u;
        __syncthreads();
    }
    const int ex = sd[t] - pr;
    if (i0 <= G) { gstart[i0] = ex;      if (i0 < G) gcur[i0] = ex; }
    if (i1 <= G) { gstart[i1] = ex + v0; if (i1 < G) gcur[i1] = ex + v0; }
}

// ---------------- K3: coarse bucketize edges into groups ----------------
// Packs (src<<6 | dst&63). P1B=256 blocks (r4-proven; r7's B3=64 left
// 3/4 of the CUs idle and cost ~19us). Per-(block,group) runs are
// contiguous: global atomic reserves the run, LDS counter fills it.
__global__ __launch_bounds__(1024) void bucketize_kernel(
    const int* __restrict__ idx, int* __restrict__ gcur,
    int* __restrict__ gbuf, int E, int G) {
    __shared__ int hist[GCAP], base[GCAP];
    const int t = threadIdx.x, b = blockIdx.x;
    for (int i = t; i < G; i += 1024) hist[i] = 0;
    __syncthreads();
    const int CH = (E + P1B - 1) / P1B;
    const int e0 = b * CH, e1 = min(E, e0 + CH);
    for (int e = e0 + t; e < e1; e += 1024)
        atomicAdd(&hist[idx[E + e] >> GSH], 1);
    __syncthreads();
    for (int i = t; i < G; i += 1024) {
        const int c = hist[i];
        base[i] = c ? atomicAdd(&gcur[i], c) : 0;
        hist[i] = 0;
    }
    __syncthreads();
    for (int e = e0 + t; e < e1; e += 1024) {
        const int dst = idx[E + e];
        const int src = idx[e];
        const int g = dst >> GSH;
        const int pos = base[g] + atomicAdd(&hist[g], 1);
        gbuf[pos] = (src << GSH) | (dst & (GS - 1));   // src < 2^(32-GSH)
    }
}

// ---------------- K4: half-group counting-sort + register gather --------
// Round-4 proven body; ONE change: gather batch depth 8 -> 16 (16
// outstanding global_load_dword per wave). r4 showed occupancy isn't the
// limit; r5/r7 showed instruction-mix isn't; MLP depth is the untested
// axis for this latency-dominated (43% HBM / 40% LLC) gather.
__global__ __launch_bounds__(256) void aggregate_kernel(
    const unsigned* __restrict__ hbuf, const int* __restrict__ gbuf,
    const int* __restrict__ gstart, unsigned* __restrict__ mbuf, int N) {
    __shared__ int elds[ELCAP];                    // 3 KB sorted src
    __shared__ int hist[AGS], segstart[AGS], cur[AGS];
    const int t = threadIdx.x, w = t >> 6, l = t & 63;
    const int b = blockIdx.x;
    const int g = b >> 1, half = b & 1;
    const int n0 = b << 5;                         // = g*64 + half*32
    const int e0 = gstart[g], cnt = gstart[g + 1] - e0;

    if (t < AGS) hist[t] = 0;
    __syncthreads();
    for (int i = t; i < cnt; i += 256) {
        const int r = gbuf[e0 + i] & (GS - 1);
        if ((r >> 5) == half) atomicAdd(&hist[r & (AGS - 1)], 1);
    }
    __syncthreads();
    if (t < AGS) cur[t] = hist[t];
    __syncthreads();
    for (int off = 1; off < AGS; off <<= 1) {
        int u = (t < AGS && t >= off) ? cur[t - off] : 0;
        __syncthreads();
        if (t < AGS) cur[t] += u;
        __syncthreads();
    }
    if (t < AGS) { segstart[t] = cur[t] - hist[t]; cur[t] = segstart[t]; }
    __syncthreads();
    for (int i = t; i < cnt; i += 256) {
        const int pk = gbuf[e0 + i];
        const int r = pk & (GS - 1);
        if ((r >> 5) == half) {
            const int pos = atomicAdd(&cur[r & (AGS - 1)], 1);
            if (pos < ELCAP) elds[pos] = pk >> GSH;
        }
    }
    __syncthreads();

    // wave w gathers nodes w*8 .. w*8+7 (register accumulate, 16-deep ILP)
    for (int i = 0; i < 8; i++) {
        const int ln = w * 8 + i;
        const int node = n0 + ln;
        const int sp = segstart[ln];
        int dend = sp + hist[ln];
        if (dend > ELCAP) dend = ELCAP;
        float a0 = 0.f, a1 = 0.f;
        int j = sp;
        for (; j + 16 <= dend; j += 16) {
            unsigned p[16];
            #pragma unroll
            for (int k = 0; k < 16; k++)
                p[k] = hbuf[(size_t)elds[j + k] * 64 + l];  // uniform elds -> broadcast
            #pragma unroll
            for (int k = 0; k < 16; k++) {
                a0 += bf2f((unsigned short)(p[k] & 0xffffu));
                a1 += bf2f((unsigned short)(p[k] >> 16));
            }
        }
        if (j + 8 <= dend) {
            unsigned p[8];
            #pragma unroll
            for (int k = 0; k < 8; k++)
                p[k] = hbuf[(size_t)elds[j + k] * 64 + l];
            #pragma unroll
            for (int k = 0; k < 8; k++) {
                a0 += bf2f((unsigned short)(p[k] & 0xffffu));
                a1 += bf2f((unsigned short)(p[k] >> 16));
            }
            j += 8;
        }
        for (; j < dend; j++) {
            unsigned p = hbuf[(size_t)elds[j] * 64 + l];
            a0 += bf2f((unsigned short)(p & 0xffffu));
            a1 += bf2f((unsigned short)(p >> 16));
        }
        const int dv = hist[ln];
        const float inv = (dv > 0) ? 1.f / (float)dv : 0.f;  // same quantization as before
        if (node < N)
            mbuf[(size_t)node * 64 + l] =
                (unsigned)f2bf(a0 * inv) | ((unsigned)f2bf(a1 * inv) << 16);
    }
}

// ---------------- K5: dense MFMA  out = [mean||h] @ Wcat^T + bl + x -----
__global__ __launch_bounds__(256) void mm_kernel(
    float* __restrict__ out, const unsigned* __restrict__ hbuf,
    const unsigned* __restrict__ mbuf, const float* __restrict__ x,
    const unsigned short* __restrict__ wsb, const float* __restrict__ bl, int N) {
    const int t = threadIdx.x, w = t >> 6, l = t & 63;
    const int rowbase = blockIdx.x * 64 + w * 16;
    if (rowbase >= N) return;
    const int r = l & 15, q = l >> 4;
    const int arow = min(rowbase + r, N - 1);
    const unsigned short* mp = (const unsigned short*)mbuf + (size_t)arow * 128 + q * 8;
    const unsigned short* hp = (const unsigned short*)hbuf + (size_t)arow * 128 + q * 8;
    short8 af[8];                          // A-frag: row=lane&15, k=(lane>>4)*8+j
    #pragma unroll
    for (int c = 0; c < 4; c++) af[c]     = *(const short8*)(mp + c * 32);
    #pragma unroll
    for (int c = 0; c < 4; c++) af[4 + c] = *(const short8*)(hp + c * 32);
    #pragma unroll
    for (int cc = 0; cc < 8; cc++) {       // 8 col-tiles of 16
        float4v acc = {0.f, 0.f, 0.f, 0.f};
        const short8* bw = (const short8*)wsb + (size_t)cc * 512;
        #pragma unroll
        for (int c = 0; c < 8; c++)
            acc = __builtin_amdgcn_mfma_f32_16x16x32_bf16(af[c], bw[c * 64 + l], acc, 0, 0, 0);
        const int col = cc * 16 + r;
        const float blv = bl[col];
        #pragma unroll
        for (int rr = 0; rr < 4; rr++) {   // C/D: col=lane&15, row=(lane>>4)*4+rr
            const int row = rowbase + q * 4 + rr;
            if (row < N)
                out[(size_t)row * 128 + col] = acc[rr] + blv + x[(size_t)row * 128 + col];
        }
    }
}

extern "C" void kernel_launch(void* const* d_in, const int* in_sizes, int n_in,
                              void* d_out, int out_size, void* d_ws, size_t ws_size,
                              hipStream_t stream) {
    const float* x     = (const float*)d_in[0];
    const int*   ei    = (const int*)d_in[1];
    const float* gamma = (const float*)d_in[2];
    const float* beta  = (const float*)d_in[3];
    const float* Wl    = (const float*)d_in[4];
    const float* bl    = (const float*)d_in[5];
    const float* Wr    = (const float*)d_in[6];
    float* out = (float*)d_out;

    const int C = 128;
    const int N = in_sizes[0] / C;          // 100000
    const int E = in_sizes[1] / 2;          // 1600000
    const int G = (N + GS - 1) >> GSH;      // 1563 groups

    char* ws = (char*)d_ws;
    size_t off = 0;
    unsigned* hbuf = (unsigned*)(ws + off); off += (size_t)N * 256;   // 25.6 MB bf16 h
    unsigned* mbuf = (unsigned*)(ws + off); off += (size_t)N * 256;   // 25.6 MB bf16 mean
    int* gbuf      = (int*)(ws + off);      off += (size_t)E * 4;     // 6.4 MB packed edges
    int* gdeg      = (int*)(ws + off);      off += GCAP * 4;
    int* gstart    = (int*)(ws + off);      off += GCAP * 4;
    int* gcur      = (int*)(ws + off);      off += GCAP * 4;
    unsigned short* wsb = (unsigned short*)(ws + off);                // 64 KB packed W

    const int LNB = (N + 3) / 4;            // 25000 LN blocks (4 rows each)

    hipMemsetAsync(gdeg, 0, GCAP * 4, stream);
    fused_pre_kernel<<<P1B + LNB + 16, 256, 0, stream>>>(
        x, gamma, beta, hbuf, ei, gdeg, Wl, Wr, wsb, N, E, LNB, G);
    gscan_kernel<<<1, 1024, 0, stream>>>(gdeg, gstart, gcur, G);
    bucketize_kernel<<<P1B, 1024, 0, stream>>>(ei, gcur, gbuf, E, G);
    aggregate_kernel<<<2 * G, 256, 0, stream>>>(hbuf, gbuf, gstart, mbuf, N);
    mm_kernel<<<(N + 63) / 64, 256, 0, stream>>>(out, hbuf, mbuf, x, wsb, bl, N);
}

// Round 9
// 249.980 us; speedup vs baseline: 1.1223x; 1.0234x over previous
//
#include <hip/hip_runtime.h>

typedef __attribute__((ext_vector_type(8))) short short8;
typedef __attribute__((ext_vector_type(4))) float float4v;

#define P1B   256    // edge-chunk blocks (count + bucketize)
#define GS    64     // nodes per bucketize group (16B runs in gbuf scatter)
#define GSH   6      // log2(GS)
#define AGS   32     // nodes per aggmm block (half-group filter)
#define ELCAP 768    // LDS edge slots per half-group; mean 512, +11 sigma
#define GCAP  2048   // max groups+1 supported (N <= 131072)
#define MPAD  66     // mean_lds row pad (dwords): breaks row-stride bank conflict

__device__ __forceinline__ unsigned short f2bf(float f) {
    union { float f; unsigned u; } v; v.f = f;
    unsigned r = v.u + 0x7fffu + ((v.u >> 16) & 1u);   // round-to-nearest-even
    return (unsigned short)(r >> 16);
}
__device__ __forceinline__ float bf2f(unsigned short u) {
    union { unsigned u; float f; } v; v.u = ((unsigned)u) << 16; return v.f;
}

// ---------------- K1: fused [group-count | LN+ReLU | W-prep] ------------
__global__ __launch_bounds__(256) void fused_pre_kernel(
    const float* __restrict__ x, const float* __restrict__ gamma,
    const float* __restrict__ beta, unsigned* __restrict__ hbuf,
    const int* __restrict__ idx, int* __restrict__ gdeg,
    const float* __restrict__ Wl, const float* __restrict__ Wr,
    unsigned short* __restrict__ wsb, int N, int E, int LNB, int G) {
    const int b = blockIdx.x, t = threadIdx.x;
    if (b < P1B) {
        __shared__ int hist[GCAP];
        for (int i = t; i < G; i += 256) hist[i] = 0;
        __syncthreads();
        const int CH = (E + P1B - 1) / P1B;
        const int e0 = b * CH, e1 = min(E, e0 + CH);
        for (int e = e0 + t; e < e1; e += 256)
            atomicAdd(&hist[idx[E + e] >> GSH], 1);
        __syncthreads();
        for (int i = t; i < G; i += 256)
            if (hist[i]) atomicAdd(&gdeg[i], hist[i]);
    } else if (b < P1B + LNB) {
        const int row = (b - P1B) * 4 + (t >> 6);
        if (row >= N) return;
        const int lane = t & 63;
        const size_t base = (size_t)row * 128 + lane * 2;
        float2 v = *(const float2*)&x[base];
        float s = v.x + v.y;
        #pragma unroll
        for (int o = 32; o; o >>= 1) s += __shfl_xor(s, o, 64);
        const float mu = s * 0.0078125f;
        const float d0 = v.x - mu, d1 = v.y - mu;
        float ss = d0 * d0 + d1 * d1;
        #pragma unroll
        for (int o = 32; o; o >>= 1) ss += __shfl_xor(ss, o, 64);
        const float rs = rsqrtf(ss * 0.0078125f + 1e-5f);
        float2 g = *(const float2*)&gamma[lane * 2];
        float2 bb = *(const float2*)&beta[lane * 2];
        float h0 = fmaxf(fmaf(d0 * rs, g.x, bb.x), 0.f);
        float h1 = fmaxf(fmaf(d1 * rs, g.y, bb.y), 0.f);
        hbuf[(size_t)row * 64 + lane] = (unsigned)f2bf(h0) | ((unsigned)f2bf(h1) << 16);
    } else {
        const int s = (b - P1B - LNB) * 256 + t;     // 0..4095
        const int tc = s >> 9, c = (s >> 6) & 7, l = s & 63;
        const int n  = tc * 16 + (l & 15);
        const int k0 = c * 32 + ((l >> 4) & 3) * 8;
        const float* w = (k0 < 128) ? (Wl + (size_t)n * 128 + k0)
                                    : (Wr + (size_t)n * 128 + (k0 - 128));
        unsigned short tmp[8];
        #pragma unroll
        for (int j = 0; j < 8; j++) tmp[j] = f2bf(w[j]);
        *(short8*)&wsb[(size_t)s * 8] = *(short8*)tmp;
    }
}

// ---------------- K2: scan group totals -> gstart[G+1], gcur ------------
__global__ __launch_bounds__(1024) void gscan_kernel(
    const int* __restrict__ gdeg, int* __restrict__ gstart,
    int* __restrict__ gcur, int G) {
    __shared__ int sd[1024];
    const int t = threadIdx.x;
    const int i0 = 2 * t, i1 = 2 * t + 1;
    const int v0 = (i0 < G) ? gdeg[i0] : 0;
    const int v1 = (i1 < G) ? gdeg[i1] : 0;
    const int pr = v0 + v1;
    sd[t] = pr;
    __syncthreads();
    for (int off = 1; off < 1024; off <<= 1) {
        int u = (t >= off) ? sd[t - off] : 0;
        __syncthreads();
        sd[t] += u;
        __syncthreads();
    }
    const int ex = sd[t] - pr;
    if (i0 <= G) { gstart[i0] = ex;      if (i0 < G) gcur[i0] = ex; }
    if (i1 <= G) { gstart[i1] = ex + v0; if (i1 < G) gcur[i1] = ex + v0; }
}

// ---------------- K3: coarse bucketize edges into groups ----------------
// Packs (src<<6 | dst&63). Per-(block,group) runs are contiguous (global
// atomic reserves the run, LDS counter fills it).
__global__ __launch_bounds__(1024) void bucketize_kernel(
    const int* __restrict__ idx, int* __restrict__ gcur,
    int* __restrict__ gbuf, int E, int G) {
    __shared__ int hist[GCAP], base[GCAP];
    const int t = threadIdx.x, b = blockIdx.x;
    for (int i = t; i < G; i += 1024) hist[i] = 0;
    __syncthreads();
    const int CH = (E + P1B - 1) / P1B;
    const int e0 = b * CH, e1 = min(E, e0 + CH);
    for (int e = e0 + t; e < e1; e += 1024)
        atomicAdd(&hist[idx[E + e] >> GSH], 1);
    __syncthreads();
    for (int i = t; i < G; i += 1024) {
        const int c = hist[i];
        base[i] = c ? atomicAdd(&gcur[i], c) : 0;
        hist[i] = 0;
    }
    __syncthreads();
    for (int e = e0 + t; e < e1; e += 1024) {
        const int dst = idx[E + e];
        const int src = idx[e];
        const int g = dst >> GSH;
        const int pos = base[g] + atomicAdd(&hist[g], 1);
        gbuf[pos] = (src << GSH) | (dst & (GS - 1));   // src < 2^(32-GSH)
    }
}

// ---------------- K4: fused [counting-sort | gather | MFMA | epilogue] --
// r8's proven gather (byte-identical inner loop) + mm fused in-block:
// mean staged to padded LDS (one barrier) instead of mbuf round-trip
// (saves 51.2 MB traffic + a launch). Quantization point unchanged.
__global__ __launch_bounds__(256) void aggmm_kernel(
    const unsigned* __restrict__ hbuf, const int* __restrict__ gbuf,
    const int* __restrict__ gstart, const unsigned short* __restrict__ wsb,
    const float* __restrict__ bl, const float* __restrict__ x,
    float* __restrict__ out, int N) {
    __shared__ int elds[ELCAP];                    // 3 KB sorted src
    __shared__ int hist[AGS], segstart[AGS], cur[AGS];
    __shared__ unsigned mean_lds[AGS][MPAD];       // 8.25 KB bf16-pair mean rows
    const int t = threadIdx.x, w = t >> 6, l = t & 63;
    const int b = blockIdx.x;
    const int g = b >> 1, half = b & 1;
    const int n0 = b << 5;                         // = g*64 + half*32
    const int e0 = gstart[g], cnt = gstart[g + 1] - e0;

    if (t < AGS) hist[t] = 0;
    __syncthreads();
    for (int i = t; i < cnt; i += 256) {
        const int r = gbuf[e0 + i] & (GS - 1);
        if ((r >> 5) == half) atomicAdd(&hist[r & (AGS - 1)], 1);
    }
    __syncthreads();
    if (t < AGS) cur[t] = hist[t];
    __syncthreads();
    for (int off = 1; off < AGS; off <<= 1) {
        int u = (t < AGS && t >= off) ? cur[t - off] : 0;
        __syncthreads();
        if (t < AGS) cur[t] += u;
        __syncthreads();
    }
    if (t < AGS) { segstart[t] = cur[t] - hist[t]; cur[t] = segstart[t]; }
    __syncthreads();
    for (int i = t; i < cnt; i += 256) {
        const int pk = gbuf[e0 + i];
        const int r = pk & (GS - 1);
        if ((r >> 5) == half) {
            const int pos = atomicAdd(&cur[r & (AGS - 1)], 1);
            if (pos < ELCAP) elds[pos] = pk >> GSH;
        }
    }
    __syncthreads();

    // gather: wave w owns nodes w*8..w*8+7 (r8-identical, 16-deep ILP);
    // result staged to mean_lds instead of mbuf.
    for (int i = 0; i < 8; i++) {
        const int ln = w * 8 + i;
        const int sp = segstart[ln];
        int dend = sp + hist[ln];
        if (dend > ELCAP) dend = ELCAP;
        float a0 = 0.f, a1 = 0.f;
        int j = sp;
        for (; j + 16 <= dend; j += 16) {
            unsigned p[16];
            #pragma unroll
            for (int k = 0; k < 16; k++)
                p[k] = hbuf[(size_t)elds[j + k] * 64 + l];  // uniform elds -> broadcast
            #pragma unroll
            for (int k = 0; k < 16; k++) {
                a0 += bf2f((unsigned short)(p[k] & 0xffffu));
                a1 += bf2f((unsigned short)(p[k] >> 16));
            }
        }
        if (j + 8 <= dend) {
            unsigned p[8];
            #pragma unroll
            for (int k = 0; k < 8; k++)
                p[k] = hbuf[(size_t)elds[j + k] * 64 + l];
            #pragma unroll
            for (int k = 0; k < 8; k++) {
                a0 += bf2f((unsigned short)(p[k] & 0xffffu));
                a1 += bf2f((unsigned short)(p[k] >> 16));
            }
            j += 8;
        }
        for (; j < dend; j++) {
            unsigned p = hbuf[(size_t)elds[j] * 64 + l];
            a0 += bf2f((unsigned short)(p & 0xffffu));
            a1 += bf2f((unsigned short)(p >> 16));
        }
        const int dv = hist[ln];
        const float inv = (dv > 0) ? 1.f / (float)dv : 0.f;  // same quantization as split
        mean_lds[ln][l] = (unsigned)f2bf(a0 * inv) | ((unsigned)f2bf(a1 * inv) << 16);
    }
    __syncthreads();

    // MFMA: wave w -> row-tile rt = w>>1 (16 rows), col-half chh = w&1 (64 cols)
    const int rt = w >> 1, chh = w & 1;
    const int r = l & 15, q = l >> 4;
    const int lrow = rt * 16 + r;
    const int arow = min(n0 + lrow, N - 1);
    short8 af[8];                          // A-frag: row=lane&15, k=(lane>>4)*8+j
    #pragma unroll
    for (int c = 0; c < 4; c++)            // mean part (K 0..127) from LDS
        af[c] = *(const short8*)&mean_lds[lrow][c * 16 + q * 4];
    const unsigned short* hp = (const unsigned short*)hbuf + (size_t)arow * 128 + q * 8;
    #pragma unroll
    for (int c = 0; c < 4; c++)            // h part (K 128..255) from global
        af[4 + c] = *(const short8*)(hp + c * 32);
    #pragma unroll
    for (int cc = 0; cc < 4; cc++) {       // 4 col-tiles of 16
        const int tc = chh * 4 + cc;
        float4v acc = {0.f, 0.f, 0.f, 0.f};
        const short8* bw = (const short8*)wsb + (size_t)tc * 512;
        #pragma unroll
        for (int c = 0; c < 8; c++)
            acc = __builtin_amdgcn_mfma_f32_16x16x32_bf16(af[c], bw[c * 64 + l], acc, 0, 0, 0);
        const int col = tc * 16 + r;
        const float blv = bl[col];
        #pragma unroll
        for (int rr = 0; rr < 4; rr++) {   // C/D: col=lane&15, row=(lane>>4)*4+rr
            const int row = n0 + rt * 16 + q * 4 + rr;
            if (row < N)
                out[(size_t)row * 128 + col] = acc[rr] + blv + x[(size_t)row * 128 + col];
        }
    }
}

extern "C" void kernel_launch(void* const* d_in, const int* in_sizes, int n_in,
                              void* d_out, int out_size, void* d_ws, size_t ws_size,
                              hipStream_t stream) {
    const float* x     = (const float*)d_in[0];
    const int*   ei    = (const int*)d_in[1];
    const float* gamma = (const float*)d_in[2];
    const float* beta  = (const float*)d_in[3];
    const float* Wl    = (const float*)d_in[4];
    const float* bl    = (const float*)d_in[5];
    const float* Wr    = (const float*)d_in[6];
    float* out = (float*)d_out;

    const int C = 128;
    const int N = in_sizes[0] / C;          // 100000
    const int E = in_sizes[1] / 2;          // 1600000
    const int G = (N + GS - 1) >> GSH;      // 1563 groups

    char* ws = (char*)d_ws;
    size_t off = 0;
    unsigned* hbuf = (unsigned*)(ws + off); off += (size_t)N * 256;   // 25.6 MB bf16 h
    int* gbuf      = (int*)(ws + off);      off += (size_t)E * 4;     // 6.4 MB packed edges
    int* gdeg      = (int*)(ws + off);      off += GCAP * 4;
    int* gstart    = (int*)(ws + off);      off += GCAP * 4;
    int* gcur      = (int*)(ws + off);      off += GCAP * 4;
    unsigned short* wsb = (unsigned short*)(ws + off);                // 64 KB packed W

    const int LNB = (N + 3) / 4;            // 25000 LN blocks (4 rows each)

    hipMemsetAsync(gdeg, 0, GCAP * 4, stream);
    fused_pre_kernel<<<P1B + LNB + 16, 256, 0, stream>>>(
        x, gamma, beta, hbuf, ei, gdeg, Wl, Wr, wsb, N, E, LNB, G);
    gscan_kernel<<<1, 1024, 0, stream>>>(gdeg, gstart, gcur, G);
    bucketize_kernel<<<P1B, 1024, 0, stream>>>(ei, gcur, gbuf, E, G);
    aggmm_kernel<<<2 * G, 256, 0, stream>>>(hbuf, gbuf, gstart, wsb, bl, x, out, N);
}

// Round 10
// 233.702 us; speedup vs baseline: 1.2005x; 1.0697x over previous
//
#include <hip/hip_runtime.h>

typedef __attribute__((ext_vector_type(8))) short short8;
typedef __attribute__((ext_vector_type(4))) float float4v;

#define P1B   256    // bucketize chunk blocks (proven 1024-thread config)
#define GS    64     // nodes per bucketize group
#define GSH   6      // log2(GS)
#define CAPG  1280   // static gbuf slots per group; mean 1024, +8 sigma
#define AGS   32     // nodes per aggmm block (half-group filter)
#define ELCAP 768    // LDS edge slots per half-group; mean 512, +11 sigma
#define GCAP  2048   // max groups supported (N <= 131072)
#define MPAD  66     // mean_lds row pad (dwords): breaks row-stride bank conflict

__device__ __forceinline__ unsigned short f2bf(float f) {
    union { float f; unsigned u; } v; v.f = f;
    unsigned r = v.u + 0x7fffu + ((v.u >> 16) & 1u);   // round-to-nearest-even
    return (unsigned short)(r >> 16);
}
__device__ __forceinline__ float bf2f(unsigned short u) {
    union { unsigned u; float f; } v; v.u = ((unsigned)u) << 16; return v.f;
}

// ---------------- K1: fused [bucketize | LN+ReLU | W-prep], 1024 thr ----
// b < P1B:                 bucketize role — LDS hist over groups, run
//                          reservation via gcnt (STATIC base g*CAPG: no
//                          gdeg/gscan needed), place packed edges.
// P1B <= b < P1B+LNB16:    LayerNorm+ReLU, 16 rows/block (wave per row)
// else (4 blocks):         pack W fragments (MFMA B layout)
__global__ __launch_bounds__(1024) void pre_kernel(
    const float* __restrict__ x, const float* __restrict__ gamma,
    const float* __restrict__ beta, unsigned* __restrict__ hbuf,
    const int* __restrict__ idx, int* __restrict__ gcnt,
    int* __restrict__ gbuf, const float* __restrict__ Wl,
    const float* __restrict__ Wr, unsigned short* __restrict__ wsb,
    int N, int E, int LNB16, int G) {
    const int b = blockIdx.x, t = threadIdx.x;
    if (b < P1B) {
        __shared__ int hist[GCAP], base[GCAP];
        for (int i = t; i < G; i += 1024) hist[i] = 0;
        __syncthreads();
        const int CH = (E + P1B - 1) / P1B;
        const int e0 = b * CH, e1 = min(E, e0 + CH);
        for (int e = e0 + t; e < e1; e += 1024)
            atomicAdd(&hist[idx[E + e] >> GSH], 1);
        __syncthreads();
        for (int i = t; i < G; i += 1024) {
            const int c = hist[i];
            base[i] = c ? (i * CAPG + atomicAdd(&gcnt[i], c)) : 0;
            hist[i] = 0;
        }
        __syncthreads();
        for (int e = e0 + t; e < e1; e += 1024) {
            const int dst = idx[E + e];
            const int src = idx[e];
            const int g = dst >> GSH;
            const int pos = base[g] + atomicAdd(&hist[g], 1);
            if (pos < (g + 1) * CAPG)                      // +8s overflow guard
                gbuf[pos] = (src << GSH) | (dst & (GS - 1));
        }
    } else if (b < P1B + LNB16) {
        const int row = (b - P1B) * 16 + (t >> 6);
        if (row >= N) return;
        const int lane = t & 63;
        const size_t bse = (size_t)row * 128 + lane * 2;
        float2 v = *(const float2*)&x[bse];
        float s = v.x + v.y;
        #pragma unroll
        for (int o = 32; o; o >>= 1) s += __shfl_xor(s, o, 64);
        const float mu = s * 0.0078125f;
        const float d0 = v.x - mu, d1 = v.y - mu;
        float ss = d0 * d0 + d1 * d1;
        #pragma unroll
        for (int o = 32; o; o >>= 1) ss += __shfl_xor(ss, o, 64);
        const float rs = rsqrtf(ss * 0.0078125f + 1e-5f);
        float2 g = *(const float2*)&gamma[lane * 2];
        float2 bb = *(const float2*)&beta[lane * 2];
        float h0 = fmaxf(fmaf(d0 * rs, g.x, bb.x), 0.f);
        float h1 = fmaxf(fmaf(d1 * rs, g.y, bb.y), 0.f);
        hbuf[(size_t)row * 64 + lane] = (unsigned)f2bf(h0) | ((unsigned)f2bf(h1) << 16);
    } else {
        const int s = (b - P1B - LNB16) * 1024 + t;  // 0..4095
        const int tc = s >> 9, c = (s >> 6) & 7, l = s & 63;
        const int n  = tc * 16 + (l & 15);
        const int k0 = c * 32 + ((l >> 4) & 3) * 8;
        const float* w = (k0 < 128) ? (Wl + (size_t)n * 128 + k0)
                                    : (Wr + (size_t)n * 128 + (k0 - 128));
        unsigned short tmp[8];
        #pragma unroll
        for (int j = 0; j < 8; j++) tmp[j] = f2bf(w[j]);
        *(short8*)&wsb[(size_t)s * 8] = *(short8*)tmp;
    }
}

// ---------------- K2: fused [counting-sort | gather | MFMA | epilogue] --
// r9-proven body; only the edge-window source changed: e0 = g*CAPG,
// cnt = min(gcnt[g], CAPG) (static bases replace gstart).
__global__ __launch_bounds__(256) void aggmm_kernel(
    const unsigned* __restrict__ hbuf, const int* __restrict__ gbuf,
    const int* __restrict__ gcnt, const unsigned short* __restrict__ wsb,
    const float* __restrict__ bl, const float* __restrict__ x,
    float* __restrict__ out, int N) {
    __shared__ int elds[ELCAP];                    // 3 KB sorted src
    __shared__ int hist[AGS], segstart[AGS], cur[AGS];
    __shared__ unsigned mean_lds[AGS][MPAD];       // 8.25 KB bf16-pair mean rows
    const int t = threadIdx.x, w = t >> 6, l = t & 63;
    const int b = blockIdx.x;
    const int g = b >> 1, half = b & 1;
    const int n0 = b << 5;                         // = g*64 + half*32
    const int e0 = g * CAPG;
    const int cnt = min(gcnt[g], CAPG);

    if (t < AGS) hist[t] = 0;
    __syncthreads();
    for (int i = t; i < cnt; i += 256) {
        const int r = gbuf[e0 + i] & (GS - 1);
        if ((r >> 5) == half) atomicAdd(&hist[r & (AGS - 1)], 1);
    }
    __syncthreads();
    if (t < AGS) cur[t] = hist[t];
    __syncthreads();
    for (int off = 1; off < AGS; off <<= 1) {
        int u = (t < AGS && t >= off) ? cur[t - off] : 0;
        __syncthreads();
        if (t < AGS) cur[t] += u;
        __syncthreads();
    }
    if (t < AGS) { segstart[t] = cur[t] - hist[t]; cur[t] = segstart[t]; }
    __syncthreads();
    for (int i = t; i < cnt; i += 256) {
        const int pk = gbuf[e0 + i];
        const int r = pk & (GS - 1);
        if ((r >> 5) == half) {
            const int pos = atomicAdd(&cur[r & (AGS - 1)], 1);
            if (pos < ELCAP) elds[pos] = pk >> GSH;
        }
    }
    __syncthreads();

    // gather: wave w owns nodes w*8..w*8+7 (register accumulate, 16-deep ILP)
    for (int i = 0; i < 8; i++) {
        const int ln = w * 8 + i;
        const int sp = segstart[ln];
        int dend = sp + hist[ln];
        if (dend > ELCAP) dend = ELCAP;
        float a0 = 0.f, a1 = 0.f;
        int j = sp;
        for (; j + 16 <= dend; j += 16) {
            unsigned p[16];
            #pragma unroll
            for (int k = 0; k < 16; k++)
                p[k] = hbuf[(size_t)elds[j + k] * 64 + l];  // uniform elds -> broadcast
            #pragma unroll
            for (int k = 0; k < 16; k++) {
                a0 += bf2f((unsigned short)(p[k] & 0xffffu));
                a1 += bf2f((unsigned short)(p[k] >> 16));
            }
        }
        if (j + 8 <= dend) {
            unsigned p[8];
            #pragma unroll
            for (int k = 0; k < 8; k++)
                p[k] = hbuf[(size_t)elds[j + k] * 64 + l];
            #pragma unroll
            for (int k = 0; k < 8; k++) {
                a0 += bf2f((unsigned short)(p[k] & 0xffffu));
                a1 += bf2f((unsigned short)(p[k] >> 16));
            }
            j += 8;
        }
        for (; j < dend; j++) {
            unsigned p = hbuf[(size_t)elds[j] * 64 + l];
            a0 += bf2f((unsigned short)(p & 0xffffu));
            a1 += bf2f((unsigned short)(p >> 16));
        }
        const int dv = hist[ln];
        const float inv = (dv > 0) ? 1.f / (float)dv : 0.f;  // same quantization as split
        mean_lds[ln][l] = (unsigned)f2bf(a0 * inv) | ((unsigned)f2bf(a1 * inv) << 16);
    }
    __syncthreads();

    // MFMA: wave w -> row-tile rt = w>>1 (16 rows), col-half chh = w&1 (64 cols)
    const int rt = w >> 1, chh = w & 1;
    const int r = l & 15, q = l >> 4;
    const int lrow = rt * 16 + r;
    const int arow = min(n0 + lrow, N - 1);
    short8 af[8];                          // A-frag: row=lane&15, k=(lane>>4)*8+j
    #pragma unroll
    for (int c = 0; c < 4; c++)            // mean part (K 0..127) from LDS
        af[c] = *(const short8*)&mean_lds[lrow][c * 16 + q * 4];
    const unsigned short* hp = (const unsigned short*)hbuf + (size_t)arow * 128 + q * 8;
    #pragma unroll
    for (int c = 0; c < 4; c++)            // h part (K 128..255) from global
        af[4 + c] = *(const short8*)(hp + c * 32);
    #pragma unroll
    for (int cc = 0; cc < 4; cc++) {       // 4 col-tiles of 16
        const int tc = chh * 4 + cc;
        float4v acc = {0.f, 0.f, 0.f, 0.f};
        const short8* bw = (const short8*)wsb + (size_t)tc * 512;
        #pragma unroll
        for (int c = 0; c < 8; c++)
            acc = __builtin_amdgcn_mfma_f32_16x16x32_bf16(af[c], bw[c * 64 + l], acc, 0, 0, 0);
        const int col = tc * 16 + r;
        const float blv = bl[col];
        #pragma unroll
        for (int rr = 0; rr < 4; rr++) {   // C/D: col=lane&15, row=(lane>>4)*4+rr
            const int row = n0 + rt * 16 + q * 4 + rr;
            if (row < N)
                out[(size_t)row * 128 + col] = acc[rr] + blv + x[(size_t)row * 128 + col];
        }
    }
}

extern "C" void kernel_launch(void* const* d_in, const int* in_sizes, int n_in,
                              void* d_out, int out_size, void* d_ws, size_t ws_size,
                              hipStream_t stream) {
    const float* x     = (const float*)d_in[0];
    const int*   ei    = (const int*)d_in[1];
    const float* gamma = (const float*)d_in[2];
    const float* beta  = (const float*)d_in[3];
    const float* Wl    = (const float*)d_in[4];
    const float* bl    = (const float*)d_in[5];
    const float* Wr    = (const float*)d_in[6];
    float* out = (float*)d_out;

    const int C = 128;
    const int N = in_sizes[0] / C;          // 100000
    const int E = in_sizes[1] / 2;          // 1600000
    const int G = (N + GS - 1) >> GSH;      // 1563 groups

    char* ws = (char*)d_ws;
    size_t off = 0;
    unsigned* hbuf = (unsigned*)(ws + off); off += (size_t)N * 256;       // 25.6 MB bf16 h
    int* gbuf      = (int*)(ws + off);      off += (size_t)G * CAPG * 4;  // 8.0 MB packed edges
    int* gcnt      = (int*)(ws + off);      off += GCAP * 4;
    unsigned short* wsb = (unsigned short*)(ws + off);                    // 64 KB packed W

    const int LNB16 = (N + 15) / 16;        // 6250 LN blocks (16 rows each)

    hipMemsetAsync(gcnt, 0, (size_t)G * 4, stream);
    pre_kernel<<<P1B + LNB16 + 4, 1024, 0, stream>>>(
        x, gamma, beta, hbuf, ei, gcnt, gbuf, Wl, Wr, wsb, N, E, LNB16, G);
    aggmm_kernel<<<2 * G, 256, 0, stream>>>(hbuf, gbuf, gcnt, wsb, bl, x, out, N);
}